// Round 8
// baseline (337.620 us; speedup 1.0000x reference)
//
#include <hip/hip_runtime.h>
#include <cstdint>
#include <cstddef>

#define B_ 4
#define T_ 2048
#define C_ 1024
#define M_ (B_ * T_)   // 8192 rows
#define HALF_ 8
#define W_ 17
#define QKV_STRIDE 3072

typedef unsigned short u16;
typedef _Float16 half8 __attribute__((ext_vector_type(8)));
typedef _Float16 half2_t __attribute__((ext_vector_type(2)));
typedef float f32x16 __attribute__((ext_vector_type(16)));

__device__ __forceinline__ float dot16(half8 a, half8 b, float acc) {
#if __has_builtin(__builtin_amdgcn_fdot2)
    const half2_t* pa = (const half2_t*)&a;
    const half2_t* pb = (const half2_t*)&b;
#pragma unroll
    for (int e = 0; e < 4; ++e) acc = __builtin_amdgcn_fdot2(pa[e], pb[e], acc, false);
#else
#pragma unroll
    for (int e = 0; e < 8; ++e) acc += (float)a[e] * (float)b[e];
#endif
    return acc;
}

__device__ __forceinline__ ushort4 cvt4(float4 v) {
    ushort4 o;
    _Float16 a = (_Float16)v.x; o.x = __builtin_bit_cast(unsigned short, a);
    _Float16 b = (_Float16)v.y; o.y = __builtin_bit_cast(unsigned short, b);
    _Float16 c = (_Float16)v.z; o.z = __builtin_bit_cast(unsigned short, c);
    _Float16 d = (_Float16)v.w; o.w = __builtin_bit_cast(unsigned short, d);
    return o;
}

// ---------------- fused prologue ----------------
// blocks [0,8192): x fp32->fp16
// blocks [8192,10240): Wq/Wk/Wv/Wo -> fragment-major fp16 (as R7)
// blocks [10240,10252): bias concat
__global__ void prologue(const float* __restrict__ x,
                         const float* __restrict__ Wq, const float* __restrict__ Wk,
                         const float* __restrict__ Wv, const float* __restrict__ Wo,
                         const float* __restrict__ bq, const float* __restrict__ bk,
                         const float* __restrict__ bv,
                         u16* __restrict__ xh, u16* __restrict__ wfq,
                         u16* __restrict__ wfo, float* __restrict__ bcat) {
    const int blk = blockIdx.x;
    if (blk < 8192) {
        int j = blk * 256 + threadIdx.x;
        ((ushort4*)xh)[j] = cvt4(((const float4*)x)[j]);
        return;
    }
    if (blk >= 10240) {
        int i = (blk - 10240) * 256 + threadIdx.x;
        const float* src = (i < 1024) ? bq : (i < 2048) ? bk : bv;
        bcat[i] = src[i & 1023];
        return;
    }
    // weight fragment conversion: chunk (nt,ks,lane) -> 16B at ((nt*64+ks)*64+lane)*8
    int c = (blk - 8192) * 256 + threadIdx.x;   // 524288 chunks
    const float* src;
    u16* dst;
    int cc;
    if (c < 393216) {
        int mat = c / 131072;
        src = (mat == 0) ? Wq : (mat == 1) ? Wk : Wv;
        dst = wfq;  cc = c;  c = c % 131072;
    } else {
        src = Wo;  dst = wfo;  cc = c - 393216;  c = cc;
    }
    const int nt_local = c >> 12;
    const int ks   = (c >> 6) & 63;
    const int lane = c & 63;
    const int row = nt_local * 32 + (lane & 31);
    const int col = ks * 16 + (lane >> 5) * 8;
    const float4* s = (const float4*)(src + (size_t)row * C_ + col);
    ushort4* d = (ushort4*)(dst + (size_t)cc * 8);
    d[0] = cvt4(s[0]);
    d[1] = cvt4(s[1]);
}

// ---------------- panel GEMM: 128x128 block tile, BK=128 A-panel ----------------
// AITER-style barrier economy: 8 barriers per K=1024 (vs 64); 32 MFMA per wave
// per barrier window. A: 32 KB LDS panel, register-prefetched (8 uint4/thread),
// physical chunk id = pass*256 + tid (contiguous writes, conflict-free), logical
// (row r, chunk c) at q = r*16 + (c ^ (r&15)) -> reads 2-way only.
// B: fragment-major direct from global (no LDS, no barrier dependency).
template <int OUT_F16>
__global__ __launch_bounds__(256) void gemm_panel(
    const u16* __restrict__ A, const u16* __restrict__ Bfrag,
    const float* __restrict__ bias, void* __restrict__ Cout,
    int Ndim, int Kdim)
{
    __shared__ __align__(16) u16 As[128 * 128];   // 32 KB

    const int tid  = threadIdx.x;
    const int lane = tid & 63;
    const int wave = tid >> 6;
    const int m0 = blockIdx.y * 128;
    const int wm = (wave >> 1) * 64;
    const int wnt = blockIdx.x * 4 + (wave & 1) * 2;   // base 32-wide n-tile

    // stager: thread t covers rows p*16 + (t>>4), logical chunk (t&15)^(t>>4&15)
    const int srow = tid >> 4;                 // 0..15 (row mod 16)
    const int clog = (tid & 15) ^ srow;        // permuted so LDS writes are lane-major
    const u16* Ast = A + (size_t)(m0 + srow) * Kdim + clog * 8;
    const size_t pskip = (size_t)16 * Kdim;    // +16 rows
    uint4* AsW = (uint4*)As + tid;             // + p*256 per pass

    const int nks = Kdim >> 4;
    const u16* Bf0 = Bfrag + ((size_t)(wnt + 0) * nks) * 512 + lane * 8;
    const u16* Bf1 = Bfrag + ((size_t)(wnt + 1) * nks) * 512 + lane * 8;

    f32x16 acc[2][2];
#pragma unroll
    for (int i = 0; i < 2; ++i)
#pragma unroll
        for (int j = 0; j < 2; ++j)
#pragma unroll
            for (int r = 0; r < 16; ++r) acc[i][j][r] = 0.f;

    const int rl = lane & 31;
    const int hi = lane >> 5;
    const int sx = lane & 15;    // == row&15 for the rows this lane reads

    uint4 pf[8];
#pragma unroll
    for (int p = 0; p < 8; ++p)
        pf[p] = *(const uint4*)(Ast + (size_t)p * pskip);

    for (int k0 = 0; k0 < Kdim; k0 += 128) {
        if (k0) __syncthreads();               // panel fully consumed
#pragma unroll
        for (int p = 0; p < 8; ++p)
            AsW[p * 256] = pf[p];              // contiguous 16B chunks
        __syncthreads();

        if (k0 + 128 < Kdim) {                 // prefetch next panel during compute
#pragma unroll
            for (int p = 0; p < 8; ++p)
                pf[p] = *(const uint4*)(Ast + k0 + 128 + (size_t)p * pskip);
        }

        const int ksb = k0 >> 4;
#pragma unroll
        for (int ks = 0; ks < 8; ++ks) {
            half8 b0 = *(const half8*)(Bf0 + (size_t)(ksb + ks) * 512);
            half8 b1 = *(const half8*)(Bf1 + (size_t)(ksb + ks) * 512);
            const int pch = (ks * 2 + hi) ^ sx;
            half8 a0 = *(const half8*)&As[((wm + rl) * 16 + pch) * 8];
            half8 a1 = *(const half8*)&As[((wm + 32 + rl) * 16 + pch) * 8];
            acc[0][0] = __builtin_amdgcn_mfma_f32_32x32x16_f16(a0, b0, acc[0][0], 0, 0, 0);
            acc[0][1] = __builtin_amdgcn_mfma_f32_32x32x16_f16(a0, b1, acc[0][1], 0, 0, 0);
            acc[1][0] = __builtin_amdgcn_mfma_f32_32x32x16_f16(a1, b0, acc[1][0], 0, 0, 0);
            acc[1][1] = __builtin_amdgcn_mfma_f32_32x32x16_f16(a1, b1, acc[1][1], 0, 0, 0);
        }
    }

    // C/D: col = lane&31, row = (reg&3) + 8*(reg>>2) + 4*(lane>>5)  [m74/m101]
#pragma unroll
    for (int i = 0; i < 2; ++i) {
#pragma unroll
        for (int j = 0; j < 2; ++j) {
            const int col = (wnt + j) * 32 + (lane & 31);
            const float bv = bias[col];
#pragma unroll
            for (int reg = 0; reg < 16; ++reg) {
                const int row = m0 + wm + i * 32 + (reg & 3) + 8 * (reg >> 2) + 4 * (lane >> 5);
                float val = acc[i][j][reg] + bv;
                if (OUT_F16) {
                    _Float16 h = (_Float16)val;
                    ((u16*)Cout)[(size_t)row * Ndim + col] = __builtin_bit_cast(unsigned short, h);
                } else {
                    ((float*)Cout)[(size_t)row * Ndim + col] = val;
                }
            }
        }
    }
}

// ---------------- windowed attention: one wave per token, branchless ----
__global__ __launch_bounds__(256) void attn_local(
    const u16* __restrict__ qkv, u16* __restrict__ ctx)
{
    const int wid  = blockIdx.x * 4 + (threadIdx.x >> 6);
    const int lane = threadIdx.x & 63;
    const int b = wid >> 11;
    const int t = wid & (T_ - 1);
    const int base = b * T_;
    const size_t qrow = (size_t)(base + t) * QKV_STRIDE;
    const int c0 = lane * 8;

    half8 q0 = *(const half8*)(qkv + qrow + c0);
    half8 q1 = *(const half8*)(qkv + qrow + 512 + c0);

    float s[W_];
#pragma unroll
    for (int o = 0; o < W_; ++o) {
        int j = t - HALF_ + o;
        int jc = min(max(j, 0), T_ - 1);
        const size_t kb = (size_t)(base + jc) * QKV_STRIDE + 1024;
        half8 k0v = *(const half8*)(qkv + kb + c0);
        half8 k1v = *(const half8*)(qkv + kb + 512 + c0);
        float d = dot16(q1, k1v, dot16(q0, k0v, 0.f));
#pragma unroll
        for (int off = 32; off > 0; off >>= 1)
            d += __shfl_xor(d, off);
        s[o] = (j == jc) ? d * 0.03125f : -3.0e38f;
    }

    float mx = s[0];
#pragma unroll
    for (int o = 1; o < W_; ++o) mx = fmaxf(mx, s[o]);
    float den = 0.f;
#pragma unroll
    for (int o = 0; o < W_; ++o) den += __expf(s[o] - mx);
    const float inv = 1.f / den;

    float acc0[8], acc1[8];
#pragma unroll
    for (int e = 0; e < 8; ++e) { acc0[e] = 0.f; acc1[e] = 0.f; }
#pragma unroll
    for (int o = 0; o < W_; ++o) {
        int j = t - HALF_ + o;
        int jc = min(max(j, 0), T_ - 1);
        const float wt = __expf(s[o] - mx) * inv;
        const size_t vb_ = (size_t)(base + jc) * QKV_STRIDE + 2048;
        half8 v0 = *(const half8*)(qkv + vb_ + c0);
        half8 v1 = *(const half8*)(qkv + vb_ + 512 + c0);
#pragma unroll
        for (int e = 0; e < 8; ++e) {
            acc0[e] += wt * (float)v0[e];
            acc1[e] += wt * (float)v1[e];
        }
    }

    const size_t crow = (size_t)(base + t) * C_;
    half8 o0, o1;
#pragma unroll
    for (int e = 0; e < 8; ++e) { o0[e] = (_Float16)acc0[e]; o1[e] = (_Float16)acc1[e]; }
    *(half8*)(ctx + crow + c0) = o0;
    *(half8*)(ctx + crow + 512 + c0) = o1;
}

// ---------------- host launch ----------------
extern "C" void kernel_launch(void* const* d_in, const int* in_sizes, int n_in,
                              void* d_out, int out_size, void* d_ws, size_t ws_size,
                              hipStream_t stream) {
    const float* x  = (const float*)d_in[0];
    const float* Wq = (const float*)d_in[1];
    const float* bq = (const float*)d_in[2];
    const float* Wk = (const float*)d_in[3];
    const float* bk = (const float*)d_in[4];
    const float* Wv = (const float*)d_in[5];
    const float* bv = (const float*)d_in[6];
    const float* Wo = (const float*)d_in[7];
    const float* bo = (const float*)d_in[8];
    float* out = (float*)d_out;

    u16* xh   = (u16*)d_ws;                         // 8M halves
    u16* wfq  = xh   + (size_t)M_ * C_;             // 3M  (Wq;Wk;Wv frag-major)
    u16* wfo  = wfq  + (size_t)3 * C_ * C_;         // 1M  (Wo frag-major)
    u16* qkvh = wfo  + (size_t)C_ * C_;             // 24M (M x 3072)
    u16* ctxh = qkvh + (size_t)M_ * QKV_STRIDE;     // 8M
    float* bcat = (float*)(ctxh + (size_t)M_ * C_); // 3072 floats

    prologue<<<10252, 256, 0, stream>>>(x, Wq, Wk, Wv, Wo, bq, bk, bv,
                                        xh, wfq, wfo, bcat);

    dim3 gqkv(QKV_STRIDE / 128, M_ / 128);   // (24, 64) = 1536 blocks
    gemm_panel<1><<<gqkv, 256, 0, stream>>>(xh, wfq, bcat, qkvh, QKV_STRIDE, C_);

    attn_local<<<M_ / 4, 256, 0, stream>>>(qkvh, ctxh);   // 2048 blocks

    dim3 go(C_ / 128, M_ / 128);             // (8, 64) = 512 blocks
    gemm_panel<0><<<go, 256, 0, stream>>>(ctxh, wfo, bo, out, C_, C_);
}

// Round 9
// 231.149 us; speedup vs baseline: 1.4606x; 1.4606x over previous
//
#include <hip/hip_runtime.h>
#include <cstdint>
#include <cstddef>

#define B_ 4
#define T_ 2048
#define C_ 1024
#define M_ (B_ * T_)   // 8192 rows
#define HALF_ 8
#define W_ 17
#define QKV_STRIDE 3072

typedef unsigned short u16;
typedef _Float16 half8 __attribute__((ext_vector_type(8)));
typedef _Float16 half2_t __attribute__((ext_vector_type(2)));
typedef float f32x16 __attribute__((ext_vector_type(16)));

__device__ __forceinline__ float dot16(half8 a, half8 b, float acc) {
#if __has_builtin(__builtin_amdgcn_fdot2)
    const half2_t* pa = (const half2_t*)&a;
    const half2_t* pb = (const half2_t*)&b;
#pragma unroll
    for (int e = 0; e < 4; ++e) acc = __builtin_amdgcn_fdot2(pa[e], pb[e], acc, false);
#else
#pragma unroll
    for (int e = 0; e < 8; ++e) acc += (float)a[e] * (float)b[e];
#endif
    return acc;
}

__device__ __forceinline__ ushort4 cvt4(float4 v) {
    ushort4 o;
    _Float16 a = (_Float16)v.x; o.x = __builtin_bit_cast(unsigned short, a);
    _Float16 b = (_Float16)v.y; o.y = __builtin_bit_cast(unsigned short, b);
    _Float16 c = (_Float16)v.z; o.z = __builtin_bit_cast(unsigned short, c);
    _Float16 d = (_Float16)v.w; o.w = __builtin_bit_cast(unsigned short, d);
    return o;
}

// ================= fragment-major layout =================
// For mfma_f32_32x32x16_f16, operand chunk (tile mt, k-step ks) = 64 lanes
// x 8 halves contiguous at ((mt*64 + ks)*64 + lane)*8.
// Lane l holds Mat[row = mt*32 + (l&31)][k = ks*16 + (l>>5)*8 + e].
// One wave frag = one coalesced global_load_dwordx4. No LDS anywhere.

// ---------------- fused prologue ----------------
// blocks [0,4096): x fp32 -> A-frag-major fp16 (wave per (mt,ks))
// blocks [4096,6144): Wq/Wk/Wv/Wo -> B-frag-major fp16
// blocks [6144,6156): bias concat
__global__ void prologue(const float* __restrict__ x,
                         const float* __restrict__ Wq, const float* __restrict__ Wk,
                         const float* __restrict__ Wv, const float* __restrict__ Wo,
                         const float* __restrict__ bq, const float* __restrict__ bk,
                         const float* __restrict__ bv,
                         u16* __restrict__ xf, u16* __restrict__ wfq,
                         u16* __restrict__ wfo, float* __restrict__ bcat) {
    const int blk = blockIdx.x;
    const int tid = threadIdx.x;
    if (blk < 4096) {          // x -> frag-major: 16384 waves
        const int wid  = blk * 4 + (tid >> 6);
        const int lane = tid & 63;
        const int mt = wid >> 6;          // 0..255
        const int ks = wid & 63;
        const int row = mt * 32 + (lane & 31);
        const int col = ks * 16 + (lane >> 5) * 8;
        const float4* s = (const float4*)(x + (size_t)row * C_ + col);
        ushort4* d = (ushort4*)(xf + (((size_t)mt * 64 + ks) * 64 + lane) * 8);
        d[0] = cvt4(s[0]);
        d[1] = cvt4(s[1]);
        return;
    }
    if (blk >= 6144) {
        int i = (blk - 6144) * 256 + tid;
        const float* src = (i < 1024) ? bq : (i < 2048) ? bk : bv;
        bcat[i] = src[i & 1023];
        return;
    }
    // weights -> frag-major
    int c = (blk - 4096) * 256 + tid;   // 524288 chunks
    const float* src;
    u16* dst;
    int cc;
    if (c < 393216) {
        int mat = c / 131072;
        src = (mat == 0) ? Wq : (mat == 1) ? Wk : Wv;
        dst = wfq;  cc = c;  c = c % 131072;
    } else {
        src = Wo;  dst = wfo;  cc = c - 393216;  c = cc;
    }
    const int nt_local = c >> 12;
    const int ks   = (c >> 6) & 63;
    const int lane = c & 63;
    const int row = nt_local * 32 + (lane & 31);
    const int col = ks * 16 + (lane >> 5) * 8;
    const float4* s = (const float4*)(src + (size_t)row * C_ + col);
    ushort4* d = (ushort4*)(dst + (size_t)cc * 8);
    d[0] = cvt4(s[0]);
    d[1] = cvt4(s[1]);
}

// ---------------- GEMM: no LDS, no barriers ----------------
// 128x128 block tile; wave = 64x64 via 2x2 of 32x32x16. All four operand
// frags are single coalesced global loads per k-step; loop has no syncthreads
// so loads pipeline freely across iterations (vmcnt(N), not barrier drains).
template <int OUT_F16>
__global__ __launch_bounds__(256) void gemm_frag(
    const u16* __restrict__ Afrag, const u16* __restrict__ Bfrag,
    const float* __restrict__ bias, void* __restrict__ Cout,
    int Ndim, int nks)
{
    const int tid  = threadIdx.x;
    const int lane = tid & 63;
    const int wave = tid >> 6;
    const int m0 = blockIdx.y * 128;
    const int wm = (wave >> 1) * 64;
    const int mt0 = blockIdx.y * 4 + (wave >> 1) * 2;   // A tiles
    const int wnt = blockIdx.x * 4 + (wave & 1) * 2;    // B tiles

    const u16* Af0 = Afrag + ((size_t)mt0 * nks) * 512 + lane * 8;
    const u16* Af1 = Af0 + (size_t)nks * 512;
    const u16* Bf0 = Bfrag + ((size_t)wnt * nks) * 512 + lane * 8;
    const u16* Bf1 = Bf0 + (size_t)nks * 512;

    f32x16 acc00, acc01, acc10, acc11;
#pragma unroll
    for (int r = 0; r < 16; ++r) { acc00[r] = 0.f; acc01[r] = 0.f; acc10[r] = 0.f; acc11[r] = 0.f; }

#pragma unroll 4
    for (int ks = 0; ks < nks; ++ks) {
        const size_t off = (size_t)ks * 512;
        half8 a0 = *(const half8*)(Af0 + off);
        half8 a1 = *(const half8*)(Af1 + off);
        half8 b0 = *(const half8*)(Bf0 + off);
        half8 b1 = *(const half8*)(Bf1 + off);
        acc00 = __builtin_amdgcn_mfma_f32_32x32x16_f16(a0, b0, acc00, 0, 0, 0);
        acc01 = __builtin_amdgcn_mfma_f32_32x32x16_f16(a0, b1, acc01, 0, 0, 0);
        acc10 = __builtin_amdgcn_mfma_f32_32x32x16_f16(a1, b0, acc10, 0, 0, 0);
        acc11 = __builtin_amdgcn_mfma_f32_32x32x16_f16(a1, b1, acc11, 0, 0, 0);
    }

    // C/D: col = lane&31, row = (reg&3) + 8*(reg>>2) + 4*(lane>>5)  [m74/m101]
    f32x16 accs[2][2] = {{acc00, acc01}, {acc10, acc11}};
#pragma unroll
    for (int i = 0; i < 2; ++i) {
#pragma unroll
        for (int j = 0; j < 2; ++j) {
            const int col = (wnt + j) * 32 + (lane & 31);
            const float bv = bias[col];
#pragma unroll
            for (int reg = 0; reg < 16; ++reg) {
                const int row = m0 + wm + i * 32 + (reg & 3) + 8 * (reg >> 2) + 4 * (lane >> 5);
                float val = accs[i][j][reg] + bv;
                if (OUT_F16) {
                    _Float16 h = (_Float16)val;
                    ((u16*)Cout)[(size_t)row * Ndim + col] = __builtin_bit_cast(unsigned short, h);
                } else {
                    ((float*)Cout)[(size_t)row * Ndim + col] = val;
                }
            }
        }
    }
}

// ---------------- windowed attention: one wave per token ----------------
// Reads qkv row-major; writes ctx directly in A-FRAG-MAJOR layout for the Wo
// GEMM: lane's channel block c0=lane*8 -> ks=c0>>4, half=(c0>>3)&1, frag slot
// ((mt*64+ks)*64 + (m&31) + 32*half)*8.
__global__ __launch_bounds__(256) void attn_local(
    const u16* __restrict__ qkv, u16* __restrict__ ctxf)
{
    const int wid  = blockIdx.x * 4 + (threadIdx.x >> 6);
    const int lane = threadIdx.x & 63;
    const int b = wid >> 11;
    const int t = wid & (T_ - 1);
    const int base = b * T_;
    const size_t qrow = (size_t)(base + t) * QKV_STRIDE;
    const int c0 = lane * 8;

    half8 q0 = *(const half8*)(qkv + qrow + c0);
    half8 q1 = *(const half8*)(qkv + qrow + 512 + c0);

    float s[W_];
#pragma unroll
    for (int o = 0; o < W_; ++o) {
        int j = t - HALF_ + o;
        int jc = min(max(j, 0), T_ - 1);
        const size_t kb = (size_t)(base + jc) * QKV_STRIDE + 1024;
        half8 k0v = *(const half8*)(qkv + kb + c0);
        half8 k1v = *(const half8*)(qkv + kb + 512 + c0);
        float d = dot16(q1, k1v, dot16(q0, k0v, 0.f));
#pragma unroll
        for (int off = 32; off > 0; off >>= 1)
            d += __shfl_xor(d, off);
        s[o] = (j == jc) ? d * 0.03125f : -3.0e38f;
    }

    float mx = s[0];
#pragma unroll
    for (int o = 1; o < W_; ++o) mx = fmaxf(mx, s[o]);
    float den = 0.f;
#pragma unroll
    for (int o = 0; o < W_; ++o) den += __expf(s[o] - mx);
    const float inv = 1.f / den;

    float acc0[8], acc1[8];
#pragma unroll
    for (int e = 0; e < 8; ++e) { acc0[e] = 0.f; acc1[e] = 0.f; }
#pragma unroll
    for (int o = 0; o < W_; ++o) {
        int j = t - HALF_ + o;
        int jc = min(max(j, 0), T_ - 1);
        const float wt = __expf(s[o] - mx) * inv;
        const size_t vb_ = (size_t)(base + jc) * QKV_STRIDE + 2048;
        half8 v0 = *(const half8*)(qkv + vb_ + c0);
        half8 v1 = *(const half8*)(qkv + vb_ + 512 + c0);
#pragma unroll
        for (int e = 0; e < 8; ++e) {
            acc0[e] += wt * (float)v0[e];
            acc1[e] += wt * (float)v1[e];
        }
    }

    half8 o0, o1;
#pragma unroll
    for (int e = 0; e < 8; ++e) { o0[e] = (_Float16)acc0[e]; o1[e] = (_Float16)acc1[e]; }

    const int m = base + t;
    const int mt = m >> 5;
    const int rowin = (m & 31) + 32 * (lane & 1);
    const size_t ch0 = ((size_t)mt * 64 + (lane >> 1)) * 64 + rowin;       // ks = lane>>1
    const size_t ch1 = ((size_t)mt * 64 + 32 + (lane >> 1)) * 64 + rowin;  // ks = 32+lane>>1
    *(half8*)(ctxf + ch0 * 8) = o0;
    *(half8*)(ctxf + ch1 * 8) = o1;
}

// ---------------- host launch ----------------
extern "C" void kernel_launch(void* const* d_in, const int* in_sizes, int n_in,
                              void* d_out, int out_size, void* d_ws, size_t ws_size,
                              hipStream_t stream) {
    const float* x  = (const float*)d_in[0];
    const float* Wq = (const float*)d_in[1];
    const float* bq = (const float*)d_in[2];
    const float* Wk = (const float*)d_in[3];
    const float* bk = (const float*)d_in[4];
    const float* Wv = (const float*)d_in[5];
    const float* bv = (const float*)d_in[6];
    const float* Wo = (const float*)d_in[7];
    const float* bo = (const float*)d_in[8];
    float* out = (float*)d_out;

    u16* xf   = (u16*)d_ws;                         // 8M halves (frag-major)
    u16* wfq  = xf   + (size_t)M_ * C_;             // 3M  (Wq;Wk;Wv frag-major)
    u16* wfo  = wfq  + (size_t)3 * C_ * C_;         // 1M  (Wo frag-major)
    u16* qkvh = wfo  + (size_t)C_ * C_;             // 24M (M x 3072 row-major)
    u16* ctxf = qkvh + (size_t)M_ * QKV_STRIDE;     // 8M  (frag-major)
    float* bcat = (float*)(ctxf + (size_t)M_ * C_); // 3072 floats

    prologue<<<6156, 256, 0, stream>>>(x, Wq, Wk, Wv, Wo, bq, bk, bv,
                                       xf, wfq, wfo, bcat);

    dim3 gqkv(QKV_STRIDE / 128, M_ / 128);   // (24, 64) = 1536 blocks
    gemm_frag<1><<<gqkv, 256, 0, stream>>>(xf, wfq, bcat, qkvh, QKV_STRIDE, 64);

    attn_local<<<M_ / 4, 256, 0, stream>>>(qkvh, ctxf);   // 2048 blocks

    dim3 go(C_ / 128, M_ / 128);             // (8, 64) = 512 blocks
    gemm_frag<0><<<go, 256, 0, stream>>>(ctxf, wfo, bo, out, C_, 64);
}